// Round 10
// baseline (1150.336 us; speedup 1.0000x reference)
//
#include <hip/hip_runtime.h>
#include <math.h>

#define EPS 1e-4f
#define BN_EPS 1e-3f
#define LN_EPS 1e-3f

typedef float f32x4 __attribute__((ext_vector_type(4)));
typedef __bf16 bf16x8 __attribute__((ext_vector_type(8)));

__device__ __forceinline__ unsigned int bf16hi_rne(float v){
    unsigned int u = __float_as_uint(v);
    unsigned int r = u + 0x7FFFu + ((u >> 16) & 1u);
    return r & 0xFFFF0000u;                 // bf16(v) bits in top half
}
__device__ __forceinline__ unsigned int pack_hilo(float v){
    unsigned int hi = bf16hi_rne(v);
    float res = v - __uint_as_float(hi);
    unsigned int u2 = __float_as_uint(res);
    unsigned int r2 = u2 + 0x7FFFu + ((u2 >> 16) & 1u);
    return hi | (r2 >> 16);
}
__device__ __forceinline__ float unpack_hilo(unsigned int p){
    return __uint_as_float(p & 0xFFFF0000u) + __uint_as_float(p << 16);
}
__device__ __forceinline__ f32x4 mfma16(uint4 a, uint4 b, f32x4 c){
    union { uint4 u; bf16x8 v; } A, B;
    A.u = a; B.u = b;
    return __builtin_amdgcn_mfma_f32_16x16x32_bf16(A.v, B.v, c, 0, 0, 0);
}

// ---------------- K1: sp_hl = pack(BN(feat @ W_pre + b_pre))  (+ zero reduction accums) ----------------
__global__ __launch_bounds__(256) void k_pre(
    const float* __restrict__ feat, const float* __restrict__ W_pre,
    const float* __restrict__ b_pre, const float* __restrict__ g_pre,
    const float* __restrict__ be_pre, const float* __restrict__ m_pre,
    const float* __restrict__ v_pre, unsigned int* __restrict__ sphl,
    float* __restrict__ accums)
{
    __shared__ __align__(16) float ft[16][64];
    int tid = threadIdx.x;
    int r0 = blockIdx.x * 16;
    if (blockIdx.x == 0){
        for (int i = tid; i < 2176; i += 256) accums[i] = 0.f;
    }
    {
        const float4* src = (const float4*)(feat + (size_t)r0 * 64);
        ((float4*)ft)[tid] = src[tid];
    }
    __syncthreads();
    int c = tid & 127;
    int rg = tid >> 7;
    float acc[8] = {0.f,0.f,0.f,0.f,0.f,0.f,0.f,0.f};
    #pragma unroll
    for (int k = 0; k < 64; k += 4){
        float w0 = W_pre[(k+0)*128 + c];
        float w1 = W_pre[(k+1)*128 + c];
        float w2 = W_pre[(k+2)*128 + c];
        float w3 = W_pre[(k+3)*128 + c];
        #pragma unroll
        for (int j = 0; j < 8; j++){
            float4 a = *(const float4*)&ft[rg*8 + j][k];
            acc[j] += a.x*w0 + a.y*w1 + a.z*w2 + a.w*w3;
        }
    }
    float aa = g_pre[c] * rsqrtf(v_pre[c] + BN_EPS);
    float cc = (b_pre[c] - m_pre[c]) * aa + be_pre[c];
    #pragma unroll
    for (int j = 0; j < 8; j++){
        size_t row = r0 + rg*8 + j;
        sphl[row*128 + c] = pack_hilo(acc[j]*aa + cc);
    }
}

// ---------------- K1b: conv weight prep -> k-major split planes ----------------
// wpl 16B-unit index: ((t*2+pl)*16 + koct)*128 + col ; unit = 8 bf16 (k octet) of column col.
__global__ __launch_bounds__(256) void k_wprep(
    const float* __restrict__ W, uint4* __restrict__ wpl)
{
    int o = blockIdx.x*256 + threadIdx.x;       // (t, koct, col): 27*16*128
    if (o >= 27*16*128) return;
    int col = o & 127; int koct = (o >> 7) & 15; int t = o >> 11;
    float v[8];
    #pragma unroll
    for (int j = 0; j < 8; j++)
        v[j] = W[((size_t)(t*128 + koct*8 + j))*128 + col];
    unsigned int hi[4], lo[4];
    #pragma unroll
    for (int j2 = 0; j2 < 4; j2++){
        float a = v[2*j2], b = v[2*j2+1];
        unsigned int ha = bf16hi_rne(a), hb = bf16hi_rne(b);
        float ra = a - __uint_as_float(ha);
        float rb = b - __uint_as_float(hb);
        hi[j2] = (ha >> 16) | (hb & 0xFFFF0000u);
        lo[j2] = (bf16hi_rne(ra) >> 16) | (bf16hi_rne(rb) & 0xFFFF0000u);
    }
    wpl[((size_t)(t*2+0)*16 + koct)*128 + col] = make_uint4(hi[0],hi[1],hi[2],hi[3]);
    wpl[((size_t)(t*2+1)*16 + koct)*128 + col] = make_uint4(lo[0],lo[1],lo[2],lo[3]);
}

// ---------------- K1c: qkv/pe weight prep -> split-plane k-octet units ----------------
__global__ __launch_bounds__(256) void k_wprep2(
    const float* __restrict__ Wqkv, const float* __restrict__ Wp2,
    uint4* __restrict__ qwhl)
{
    int o = blockIdx.x*256 + threadIdx.x;           // 512*16 = 8192
    if (o >= 8192) return;
    int koct = o & 15, col = o >> 4;
    float v[8];
    #pragma unroll
    for (int j = 0; j < 8; j++){
        int k = koct*8 + j;
        v[j] = (col < 384) ? Wqkv[(size_t)k*384 + col] : Wp2[(size_t)k*128 + (col - 384)];
    }
    unsigned int hi[4], lo[4];
    #pragma unroll
    for (int j2 = 0; j2 < 4; j2++){
        float a = v[2*j2], b = v[2*j2+1];
        unsigned int ha = bf16hi_rne(a), hb = bf16hi_rne(b);
        float ra = a - __uint_as_float(ha);
        float rb = b - __uint_as_float(hb);
        hi[j2] = (ha >> 16) | (hb & 0xFFFF0000u);
        lo[j2] = (bf16hi_rne(ra) >> 16) | (bf16hi_rne(rb) & 0xFFFF0000u);
    }
    qwhl[o]        = make_uint4(hi[0],hi[1],hi[2],hi[3]);
    qwhl[8192 + o] = make_uint4(lo[0],lo[1],lo[2],lo[3]);
}

// ---------------- K2: fused pe + qkv via split-bf16 MFMA (verified round-6/7) ----------------
__global__ __launch_bounds__(256) void k_qkv(
    const unsigned int* __restrict__ sphl, const int* __restrict__ indices,
    const float* __restrict__ Wp1, const float* __restrict__ bp1,
    const float* __restrict__ g_pe, const float* __restrict__ be_pe,
    const float* __restrict__ m_pe, const float* __restrict__ v_pe,
    const float* __restrict__ bp2, const uint4* __restrict__ qwhl,
    const float* __restrict__ b_qkv, const float* __restrict__ scale_p,
    float* __restrict__ qb, float* __restrict__ kb, unsigned int* __restrict__ vhl)
{
    __shared__ __align__(16) unsigned int At[2][32*132];  // [0]=sp_hl, [1]=pe_hl
    __shared__ float peout[32*128];
    __shared__ float invs[128];
    __shared__ float xyzs[32][3];
    int tid = threadIdx.x;
    int r0 = blockIdx.x * 32;
    {
        const uint4* src = (const uint4*)(sphl + (size_t)r0*128);
        #pragma unroll
        for (int u = 0; u < 4; u++){
            int i = tid + 256*u;            // 1024 uint4 = 32x128 u32
            int r = i >> 5, cq = i & 31;
            *(uint4*)&At[0][r*132 + cq*4] = src[i];
        }
    }
    if (tid < 96){
        int r = tid / 3, d = tid % 3;
        xyzs[r][d] = (float)indices[(size_t)(r0 + r)*4 + 1 + d];
    }
    if (tid < 128){
        float sx = scale_p[tid];
        float sc = (sx > 20.f) ? sx : log1pf(expf(sx));
        invs[tid] = 1.f / sc;
    }
    __syncthreads();
    #pragma unroll
    for (int u = 0; u < 16; u++){
        int oi = tid + 256*u;               // 4096 = 32x128
        int r = oi >> 7, c = oi & 127;
        float dot = xyzs[r][0]*Wp1[c] + xyzs[r][1]*Wp1[128+c] + xyzs[r][2]*Wp1[256+c] + bp1[c];
        float aa = g_pe[c] * rsqrtf(v_pe[c] + BN_EPS);
        float t = (dot - m_pe[c])*aa + be_pe[c];
        At[1][r*132 + c] = pack_hilo(fmaxf(t, 0.f));
    }
    __syncthreads();

    int lane = tid & 63;
    int w = tid >> 6;                       // 0=q 1=k 2=v 3=pe
    int m = lane & 15, kq = lane >> 4;
    const unsigned int* A = &At[w == 3 ? 1 : 0][0];

    uint4 ahi[2][4], alo[2][4];
    #pragma unroll
    for (int rt = 0; rt < 2; rt++){
        #pragma unroll
        for (int ks = 0; ks < 4; ks++){
            const unsigned int* ap = &A[(rt*16 + m)*132 + ks*32 + kq*8];
            uint4 a0 = *(const uint4*)ap;
            uint4 a1 = *(const uint4*)(ap + 4);
            uint4 h, l;
            h.x = __builtin_amdgcn_perm(a0.y, a0.x, 0x07060302u);
            h.y = __builtin_amdgcn_perm(a0.w, a0.z, 0x07060302u);
            h.z = __builtin_amdgcn_perm(a1.y, a1.x, 0x07060302u);
            h.w = __builtin_amdgcn_perm(a1.w, a1.z, 0x07060302u);
            l.x = __builtin_amdgcn_perm(a0.y, a0.x, 0x05040100u);
            l.y = __builtin_amdgcn_perm(a0.w, a0.z, 0x05040100u);
            l.z = __builtin_amdgcn_perm(a1.y, a1.x, 0x05040100u);
            l.w = __builtin_amdgcn_perm(a1.w, a1.z, 0x05040100u);
            ahi[rt][ks] = h; alo[rt][ks] = l;
        }
    }

    f32x4 acc[2][8];
    #pragma unroll
    for (int rt = 0; rt < 2; rt++)
        #pragma unroll
        for (int ct = 0; ct < 8; ct++)
            acc[rt][ct] = (f32x4){0.f,0.f,0.f,0.f};

    int colg = w * 128;
    #pragma unroll
    for (int ct = 0; ct < 8; ct++){
        #pragma unroll
        for (int ks = 0; ks < 4; ks++){
            int bu = (colg + ct*16 + m)*16 + ks*4 + kq;
            uint4 bhi = qwhl[bu];
            uint4 blo = qwhl[8192 + bu];
            #pragma unroll
            for (int rt = 0; rt < 2; rt++){
                acc[rt][ct] = mfma16(ahi[rt][ks], bhi, acc[rt][ct]);
                acc[rt][ct] = mfma16(alo[rt][ks], bhi, acc[rt][ct]);
                acc[rt][ct] = mfma16(ahi[rt][ks], blo, acc[rt][ct]);
            }
        }
    }

    if (w == 3){
        #pragma unroll
        for (int ct = 0; ct < 8; ct++){
            int col = ct*16 + m;
            float bp = bp2[col];
            #pragma unroll
            for (int rt = 0; rt < 2; rt++){
                #pragma unroll
                for (int reg = 0; reg < 4; reg++){
                    int row = rt*16 + kq*4 + reg;
                    peout[row*128 + col] = acc[rt][ct][reg] + bp;
                }
            }
        }
    }
    __syncthreads();
    if (w == 0){
        #pragma unroll
        for (int ct = 0; ct < 8; ct++){
            int col = ct*16 + m;
            float bq = b_qkv[col], inv = invs[col];
            #pragma unroll
            for (int rt = 0; rt < 2; rt++){
                #pragma unroll
                for (int reg = 0; reg < 4; reg++){
                    int row = rt*16 + kq*4 + reg;
                    float v = acc[rt][ct][reg] + bq;
                    qb[(size_t)(r0 + row)*128 + col] = (fmaxf(v, 0.f) + EPS) * inv;
                }
            }
        }
    } else if (w == 1){
        #pragma unroll
        for (int ct = 0; ct < 8; ct++){
            int col = ct*16 + m;
            float bk = b_qkv[128 + col], inv = invs[col];
            #pragma unroll
            for (int rt = 0; rt < 2; rt++){
                #pragma unroll
                for (int reg = 0; reg < 4; reg++){
                    int row = rt*16 + kq*4 + reg;
                    float v = acc[rt][ct][reg] + bk + peout[row*128 + col];
                    kb[(size_t)(r0 + row)*128 + col] = (fmaxf(v, 0.f) + EPS) * inv;
                }
            }
        }
    } else if (w == 2){
        #pragma unroll
        for (int ct = 0; ct < 8; ct++){
            int col = ct*16 + m;
            float bv = b_qkv[256 + col];
            #pragma unroll
            for (int rt = 0; rt < 2; rt++){
                #pragma unroll
                for (int reg = 0; reg < 4; reg++){
                    int row = rt*16 + kq*4 + reg;
                    vhl[(size_t)(r0 + row)*128 + col] = pack_hilo(acc[rt][ct][reg] + bv);
                }
            }
        }
    }
}

// ---------------- K2b: ksum[h][e], kv[h][e][f] reductions (v from packed) ----------------
__global__ __launch_bounds__(256) void k_red(
    const float* __restrict__ kb, const unsigned int* __restrict__ vhl,
    float* __restrict__ ksum, float* __restrict__ kvm, int ntiles)
{
    __shared__ __align__(16) float kt[16][128];
    __shared__ __align__(16) unsigned int vt[16][128];
    int tid = threadIdx.x;
    int he = tid & 127, fh = tid >> 7;
    int h = he >> 4;
    float akv[8] = {0,0,0,0,0,0,0,0};
    float aks = 0.f;
    for (int ti = blockIdx.x; ti < ntiles; ti += gridDim.x){
        size_t base = (size_t)ti * 16 * 128;
        const float4* ks_ = (const float4*)(kb + base);
        const uint4* vs_ = (const uint4*)(vhl + base);
        float4* kd = (float4*)&kt[0][0];
        uint4* vd = (uint4*)&vt[0][0];
        __syncthreads();
        kd[tid] = ks_[tid]; kd[tid + 256] = ks_[tid + 256];
        vd[tid] = vs_[tid]; vd[tid + 256] = vs_[tid + 256];
        __syncthreads();
        #pragma unroll 4
        for (int r = 0; r < 16; r++){
            float kval = kt[r][he];
            const unsigned int* vr = &vt[r][h*16 + fh*8];
            #pragma unroll
            for (int j = 0; j < 8; j++){
                akv[j] += kval * unpack_hilo(vr[j]);
            }
            if (fh == 0) aks += kval;
        }
    }
    #pragma unroll
    for (int j = 0; j < 8; j++) atomicAdd(&kvm[he*16 + fh*8 + j], akv[j]);
    if (fh == 0) atomicAdd(&ksum[he], aks);
}

// ---------------- K4: 27-tap gather conv — split-plane LDS + rotation, 16x16 MFMA ----------------
// 64 rows x 128 cols per block; 4 waves = (wr:2 x wc:2), each 32 rows x 64 cols.
// Gather perm-splits packed v into hi/lo bf16 LDS planes with octet rotation (pos=(o+row)&15).
// B from pre-split k-major planes (wpl). Round-3 schedule: one barrier pair per tap, no prefetch.
__global__ __launch_bounds__(256) void k_conv(
    const unsigned int* __restrict__ vhl, const int* __restrict__ nbr,
    const uint4* __restrict__ wpl, const float* __restrict__ b_dwc,
    float* __restrict__ xb)
{
    __shared__ unsigned int pl[2][64*64];   // 2 x 16KB bf16 planes; row = 16 octets x 16B, rotated
    __shared__ int nbT[27*64];
    int tid = threadIdx.x;
    int r0 = blockIdx.x * 64;
    for (int i = tid; i < 27*64; i += 256){
        int t = i >> 6, r = i & 63;
        nbT[i] = nbr[(size_t)(r0 + r)*27 + t];
    }
    int lane = tid & 63;
    int w  = tid >> 6;
    int wr = w >> 1, wc = w & 1;
    int m  = lane & 15, kq = lane >> 4;
    int tr = tid >> 5, tc = tid & 31;

    f32x4 acc[2][4];
    #pragma unroll
    for (int rb = 0; rb < 2; rb++)
        #pragma unroll
        for (int cbi = 0; cbi < 4; cbi++)
            acc[rb][cbi] = (f32x4){0.f,0.f,0.f,0.f};

    for (int t = 0; t < 27; t++){
        __syncthreads();                    // prev compute done (and nbT ready on t=0)
        #pragma unroll
        for (int s = 0; s < 8; s++){
            int r = tr + 8*s;
            int idx = nbT[t*64 + r];
            uint4 p = make_uint4(0u,0u,0u,0u);
            if (idx >= 0) p = *(const uint4*)&vhl[(size_t)idx*128 + tc*4];
            unsigned int h0 = __builtin_amdgcn_perm(p.y, p.x, 0x07060302u);
            unsigned int h1 = __builtin_amdgcn_perm(p.w, p.z, 0x07060302u);
            unsigned int l0 = __builtin_amdgcn_perm(p.y, p.x, 0x05040100u);
            unsigned int l1 = __builtin_amdgcn_perm(p.w, p.z, 0x05040100u);
            int pos = ((tc >> 1) + r) & 15;           // rotated octet position
            int u = r*64 + pos*4 + (tc & 1)*2;
            *(uint2*)&pl[0][u] = make_uint2(h0, h1);
            *(uint2*)&pl[1][u] = make_uint2(l0, l1);
        }
        __syncthreads();                    // planes ready
        const uint4* bt = wpl + (size_t)t*2*16*128;
        #pragma unroll
        for (int ks = 0; ks < 4; ks++){
            int O = ks*4 + kq;              // k-octet for this lane
            uint4 ahi[2], alo[2];
            #pragma unroll
            for (int rb = 0; rb < 2; rb++){
                int ar = wr*32 + rb*16 + m;
                int pos = (O + ar) & 15;
                ahi[rb] = *(const uint4*)&pl[0][ar*64 + pos*4];
                alo[rb] = *(const uint4*)&pl[1][ar*64 + pos*4];
            }
            #pragma unroll
            for (int cbi = 0; cbi < 4; cbi++){
                int col = wc*64 + cbi*16 + m;
                uint4 bhi = bt[(size_t)O*128 + col];
                uint4 blo = bt[(size_t)(16 + O)*128 + col];
                #pragma unroll
                for (int rb = 0; rb < 2; rb++){
                    acc[rb][cbi] = mfma16(ahi[rb], bhi, acc[rb][cbi]);
                    acc[rb][cbi] = mfma16(alo[rb], bhi, acc[rb][cbi]);
                    acc[rb][cbi] = mfma16(ahi[rb], blo, acc[rb][cbi]);
                }
            }
        }
    }
    // epilogue: D col = lane&15, row = (lane>>4)*4 + reg (verified 16x16 mapping)
    #pragma unroll
    for (int cbi = 0; cbi < 4; cbi++){
        int col = wc*64 + cbi*16 + m;
        float bias = b_dwc[col];
        #pragma unroll
        for (int rb = 0; rb < 2; rb++){
            #pragma unroll
            for (int reg = 0; reg < 4; reg++){
                size_t row = (size_t)r0 + wr*32 + rb*16 + kq*4 + reg;
                xb[row*128 + col] = acc[rb][cbi][reg] + bias;
            }
        }
    }
}

// ---------------- K5: out = LN( (attn + conv) @ W_proj + b_proj + sp ) ----------------
__global__ __launch_bounds__(256) void k_out(
    const float* __restrict__ xb, const float* __restrict__ qb,
    const float* __restrict__ ksum, const float* __restrict__ kvm,
    const float* __restrict__ W_proj, const float* __restrict__ b_proj,
    const unsigned int* __restrict__ sphl, const float* __restrict__ g_n1,
    const float* __restrict__ b_n1, float* __restrict__ out)
{
    __shared__ __align__(16) float yt[16][128];
    __shared__ __align__(16) float qt[16][128];
    __shared__ float kvl[2048];
    __shared__ float ksl[128];
    int tid = threadIdx.x;
    int r0 = blockIdx.x * 16;
    {
        const float4* srcy = (const float4*)(xb + (size_t)r0 * 128);
        const float4* srcq = (const float4*)(qb + (size_t)r0 * 128);
        float4* dsty = (float4*)&yt[0][0];
        float4* dstq = (float4*)&qt[0][0];
        dsty[tid] = srcy[tid]; dsty[tid + 256] = srcy[tid + 256];
        dstq[tid] = srcq[tid]; dstq[tid + 256] = srcq[tid + 256];
    }
    #pragma unroll
    for (int u = 0; u < 8; u++) kvl[tid + 256*u] = kvm[tid + 256*u];
    if (tid < 128) ksl[tid] = ksum[tid];
    __syncthreads();

    int c2 = (tid & 63) * 2;
    int rg = tid >> 6;
    {
        int h = c2 >> 4, f0 = c2 & 15;
        float kv0[16], kv1[16], ks[16];
        #pragma unroll
        for (int e = 0; e < 16; e++){
            kv0[e] = kvl[(h*16 + e)*16 + f0];
            kv1[e] = kvl[(h*16 + e)*16 + f0 + 1];
            ks[e]  = ksl[h*16 + e];
        }
        float y[4][2];
        #pragma unroll
        for (int j = 0; j < 4; j++){
            int r = rg*4 + j;
            float zd = 0.f, x0 = 0.f, x1 = 0.f;
            #pragma unroll
            for (int e = 0; e < 16; e++){
                float qe = qt[r][h*16 + e];
                zd += qe * ks[e];
                x0 += qe * kv0[e];
                x1 += qe * kv1[e];
            }
            float iz = 1.f / (zd + EPS);
            y[j][0] = x0*iz + yt[r][c2];
            y[j][1] = x1*iz + yt[r][c2+1];
        }
        #pragma unroll
        for (int j = 0; j < 4; j++){
            yt[rg*4 + j][c2]     = y[j][0];
            yt[rg*4 + j][c2 + 1] = y[j][1];
        }
    }
    __syncthreads();
    float acc[4][2] = {{0,0},{0,0},{0,0},{0,0}};
    for (int k = 0; k < 128; k += 4){
        float2 w0 = *(const float2*)&W_proj[(k+0)*128 + c2];
        float2 w1 = *(const float2*)&W_proj[(k+1)*128 + c2];
        float2 w2 = *(const float2*)&W_proj[(k+2)*128 + c2];
        float2 w3 = *(const float2*)&W_proj[(k+3)*128 + c2];
        #pragma unroll
        for (int j = 0; j < 4; j++){
            float4 a = *(const float4*)&yt[rg*4 + j][k];
            acc[j][0] += a.x*w0.x + a.y*w1.x + a.z*w2.x + a.w*w3.x;
            acc[j][1] += a.x*w0.y + a.y*w1.y + a.z*w2.y + a.w*w3.y;
        }
    }
    float bp0 = b_proj[c2], bp1_ = b_proj[c2+1];
    float g0 = g_n1[c2], g1 = g_n1[c2+1], B0 = b_n1[c2], B1 = b_n1[c2+1];
    float z[4][2], s[4], ss[4];
    #pragma unroll
    for (int j = 0; j < 4; j++){
        size_t row = r0 + rg*4 + j;
        uint2 spv = *(const uint2*)&sphl[row*128 + c2];
        float z0 = acc[j][0] + bp0 + unpack_hilo(spv.x);
        float z1 = acc[j][1] + bp1_ + unpack_hilo(spv.y);
        z[j][0] = z0; z[j][1] = z1;
        s[j] = z0 + z1; ss[j] = z0*z0 + z1*z1;
    }
    #pragma unroll
    for (int m = 1; m < 64; m <<= 1){
        #pragma unroll
        for (int j = 0; j < 4; j++){
            s[j]  += __shfl_xor(s[j],  m, 64);
            ss[j] += __shfl_xor(ss[j], m, 64);
        }
    }
    #pragma unroll
    for (int j = 0; j < 4; j++){
        size_t row = r0 + rg*4 + j;
        float mu = s[j] * (1.f/128.f);
        float var = ss[j] * (1.f/128.f) - mu*mu;
        float rstd = rsqrtf(var + LN_EPS);
        float2 o;
        o.x = (z[j][0] - mu)*rstd*g0 + B0;
        o.y = (z[j][1] - mu)*rstd*g1 + B1;
        *(float2*)&out[row*128 + c2] = o;
    }
}

extern "C" void kernel_launch(void* const* d_in, const int* in_sizes, int n_in,
                              void* d_out, int out_size, void* d_ws, size_t ws_size,
                              hipStream_t stream)
{
    const float* feat    = (const float*)d_in[0];
    const int*   indices = (const int*)  d_in[1];
    const int*   nbr     = (const int*)  d_in[2];
    const float* W_pre   = (const float*)d_in[3];
    const float* b_pre   = (const float*)d_in[4];
    const float* g_pre   = (const float*)d_in[5];
    const float* be_pre  = (const float*)d_in[6];
    const float* m_pre   = (const float*)d_in[7];
    const float* v_pre   = (const float*)d_in[8];
    const float* Wp1     = (const float*)d_in[9];
    const float* bp1     = (const float*)d_in[10];
    const float* g_pe    = (const float*)d_in[11];
    const float* be_pe   = (const float*)d_in[12];
    const float* m_pe    = (const float*)d_in[13];
    const float* v_pe    = (const float*)d_in[14];
    const float* Wp2     = (const float*)d_in[15];
    const float* bp2     = (const float*)d_in[16];
    const float* W_qkv   = (const float*)d_in[17];
    const float* b_qkv   = (const float*)d_in[18];
    const float* scale_p = (const float*)d_in[19];
    const float* W_dwc   = (const float*)d_in[20];
    const float* b_dwc   = (const float*)d_in[21];
    const float* W_proj  = (const float*)d_in[22];
    const float* b_proj  = (const float*)d_in[23];
    const float* g_n1    = (const float*)d_in[24];
    const float* b_n1    = (const float*)d_in[25];
    float* out = (float*)d_out;

    int N = in_sizes[0] / 64;           // 120000
    size_t NC = (size_t)N * 128;
    float* ws   = (float*)d_ws;
    unsigned int* sphl = (unsigned int*)ws;
    float* qb   = ws + NC;
    float* kb   = ws + 2*NC;
    unsigned int* vhl = (unsigned int*)(ws + 3*NC);
    float* ksum = ws + 4*NC;
    float* kvm  = ksum + 128;
    uint4* wpl  = (uint4*)(ksum + 2560);            // 110592 uint4 = 1.77MB (16B aligned)
    uint4* qwhl = (uint4*)(ksum + 2560 + 442368);   // 16384 uint4 = 256KB
    float* xb   = kb;                   // kb dead after k_red; reuse for conv output

    k_wprep <<<216,  256, 0, stream>>>(W_dwc, wpl);
    k_wprep2<<<32,   256, 0, stream>>>(W_qkv, Wp2, qwhl);
    k_pre   <<<N/16, 256, 0, stream>>>(feat, W_pre, b_pre, g_pre, be_pre, m_pre, v_pre, sphl, ksum);
    k_qkv   <<<N/32, 256, 0, stream>>>(sphl, indices, Wp1, bp1, g_pe, be_pe, m_pe, v_pe,
                                       bp2, qwhl, b_qkv, scale_p, qb, kb, vhl);
    k_red   <<<768,  256, 0, stream>>>(kb, vhl, ksum, kvm, N/16);
    k_conv  <<<N/64, 256, 0, stream>>>(vhl, nbr, wpl, b_dwc, xb);
    k_out   <<<N/16, 256, 0, stream>>>(xb, qb, ksum, kvm, W_proj, b_proj, sphl, g_n1, b_n1, out);
}